// Round 5
// baseline (94.507 us; speedup 1.0000x reference)
//
#include <hip/hip_runtime.h>
#include <hip/hip_bf16.h>

// BlockAttention: paged KV-cache prefill attention, block-causal mask.
// B=4, LQ=512, HQ=16, HKV=8, D=128, CTX=2048, LK=2560.
// R1: XCD-aware block index + register prefetch.
// R2: swizzled K/V LDS, double-buffer, one barrier/tile.
// R3: swapped QK^T -> in-register softmax; zero-shuffle PV (pa in-lane,
//     V^T bit-permuted); cvt_pk; defer-max.
// R4: kv-split wave specialization: 8 waves = 4 q-groups x 2 kv-halves.
//     Each wave: 32 q-rows (2 subtiles) x 32-kv half per tile -> kf/vf
//     b128 reads reused across 2 subtiles (16 reads/wave/tile, was 32
//     for half the work). Wave-pair (m,l,O) merged once at end via LDS
//     scratch overlaying the K/V buffers.

#define B_    4
#define LQ_   512
#define HQ_   16
#define HKV_  8
#define D_    128
#define BLKSZ_ 256
#define BPS_  8
#define CTX_  2048
#define DIFFB_ 128
#define KT_   64
#define SCALE_ 0.08838834764831845f

typedef __attribute__((ext_vector_type(4))) float f32x4;
typedef __attribute__((ext_vector_type(8))) short bf16x8;

__device__ __forceinline__ unsigned cvt_pk2(float a, float b) {
  union { __hip_bfloat162 h; unsigned u; } x;
  x.h = __float22bfloat162_rn(float2{a, b});
  return x.u;
}
union bf8u { bf16x8 v; unsigned u[4]; };

// ---- K tile swizzle (units: shorts), 16B-chunk XOR ----
__device__ __forceinline__ int kidx(int kv, int d) {
  return kv * 128 + ((((d >> 3) ^ kv) & 15) << 3) + (d & 7);
}
// ---- V^T tile swizzle; p is the PHYSICAL (k-label) kv slot ----
__device__ __forceinline__ int vidx(int d, int p) {
  return d * 64 + ((((p >> 3) ^ d ^ (d >> 3)) & 7) << 3) + (p & 7);
}
// kv -> phys k-label within a 32-half: w=[4][3:2][1:0] -> [3:2][4][1:0]
__device__ __forceinline__ int pk32(int w) {
  return (((w >> 2) & 3) << 3) | (((w >> 4) & 1) << 2) | (w & 3);
}

__global__ __launch_bounds__(512, 2)
void block_attn_kernel(const float* __restrict__ qg,
                       const float* __restrict__ kcur,
                       const float* __restrict__ vcur,
                       const float* __restrict__ kcache,
                       const float* __restrict__ vcache,
                       const int*   __restrict__ btab,
                       float*       __restrict__ out) {
  // grid 256: blk = qb*32 + b*8 + hkv (qb high bits -> same (b,hkv) per XCD)
  const int blk  = blockIdx.x;
  const int hkv  = blk & 7;
  const int b    = (blk >> 3) & 3;
  const int qb   = blk >> 5;
  const int tid  = threadIdx.x;
  const int lane = tid & 63;
  const int wave = tid >> 6;
  const int lo   = lane & 15;
  const int hi   = lane >> 4;
  const int qg2  = wave >> 1;            // q-group 0..3
  const int kvh  = wave & 1;             // kv half 0..1
  const int hq   = hkv * 2 + (qg2 >> 1);
  const int qrow0 = qb * 64 + (qg2 & 1) * 32;   // wave's 32 q rows
  const int limit  = CTX_ + (qb / 2 + 1) * DIFFB_;
  const int ntiles = limit / KT_;

  // K buffers @0,16384; V buffers @32768,49152 (bytes). Merge scratch
  // (128 x 128 f32 = 64KB) overlays the whole region after the loop.
  __shared__ __align__(16) char smem_raw[65536];
  __shared__ float ms[8][16], ls[8][16];
  float* Os = (float*)smem_raw;

  // ---- Q fragments (scaled bf16): qf[sub][db], B-frag col=lo, k=hi*8+j ----
  bf16x8 qf[2][4];
#pragma unroll
  for (int sub = 0; sub < 2; ++sub) {
    const float* qr = qg + ((size_t)((b * LQ_ + qrow0 + sub * 16 + lo)) * HQ_ + hq) * D_;
#pragma unroll
    for (int db = 0; db < 4; ++db) {
      const int d0 = db * 32 + hi * 8;
      f32x4 a = *(const f32x4*)(qr + d0);
      f32x4 c4 = *(const f32x4*)(qr + d0 + 4);
      bf8u f;
      f.u[0] = cvt_pk2(a[0] * SCALE_, a[1] * SCALE_);
      f.u[1] = cvt_pk2(a[2] * SCALE_, a[3] * SCALE_);
      f.u[2] = cvt_pk2(c4[0] * SCALE_, c4[1] * SCALE_);
      f.u[3] = cvt_pk2(c4[2] * SCALE_, c4[3] * SCALE_);
      qf[sub][db] = f.v;
    }
  }

  f32x4 oacc[2][8];
#pragma unroll
  for (int s = 0; s < 2; ++s)
#pragma unroll
    for (int i = 0; i < 8; ++i) oacc[s][i] = (f32x4){0.f, 0.f, 0.f, 0.f};
  float mrow[2] = {-1e30f, -1e30f}, lrow[2] = {0.f, 0.f};

  // ---- staging thread mapping (block stages full 64-kv tile) ----
  const int c  = tid >> 3;              // logical kv row (0..63)
  const int e  = tid & 7;
  const int ep = ((c & 1) << 3) | e;
  const int r0 = c & ~1;
  const int pr = (r0 & 32) + pk32(r0 & 31);   // phys col (even)
  f32x4 kreg[4], vreg[4];

  auto issue_loads = [&](int t) {
    const int kbase = t * KT_;
    const float *kr, *vr0;
    if (kbase < CTX_) {
      const int pb = btab[b * BPS_ + (kbase >> 8)];
      const int ro = (kbase & 255);
      kr  = kcache + ((size_t)(pb * BLKSZ_ + ro + c)  * HKV_ + hkv) * D_;
      vr0 = vcache + ((size_t)(pb * BLKSZ_ + ro + r0) * HKV_ + hkv) * D_;
    } else {
      const int cur = kbase - CTX_;
      kr  = kcur + ((size_t)(b * LQ_ + cur + c)  * HKV_ + hkv) * D_;
      vr0 = vcur + ((size_t)(b * LQ_ + cur + r0) * HKV_ + hkv) * D_;
    }
#pragma unroll
    for (int i2 = 0; i2 < 4; ++i2)
      kreg[i2] = *(const f32x4*)(kr + (e + i2 * 8) * 4);
    const int vd0 = ep * 8;
    vreg[0] = *(const f32x4*)(vr0 + vd0);
    vreg[1] = *(const f32x4*)(vr0 + vd0 + 4);
    vreg[2] = *(const f32x4*)(vr0 + HKV_ * D_ + vd0);
    vreg[3] = *(const f32x4*)(vr0 + HKV_ * D_ + vd0 + 4);
  };

  auto write_lds = [&](int bsel) {
    short* Kb = (short*)(smem_raw + bsel * 16384);
    short* Vb = (short*)(smem_raw + 32768 + bsel * 16384);
#pragma unroll
    for (int i2 = 0; i2 < 4; ++i2) {
      const int d0 = (e + i2 * 8) * 4;
      f32x4 kv = kreg[i2];
      *(unsigned*)&Kb[kidx(c, d0)]     = cvt_pk2(kv[0], kv[1]);
      *(unsigned*)&Kb[kidx(c, d0 + 2)] = cvt_pk2(kv[2], kv[3]);
    }
    const int vd0 = ep * 8;
#pragma unroll
    for (int j = 0; j < 4; ++j) {
      *(unsigned*)&Vb[vidx(vd0 + j,     pr)] = cvt_pk2(vreg[0][j], vreg[2][j]);
      *(unsigned*)&Vb[vidx(vd0 + 4 + j, pr)] = cvt_pk2(vreg[1][j], vreg[3][j]);
    }
  };

  issue_loads(0);
  write_lds(0);
  __syncthreads();

  for (int t = 0; t < ntiles; ++t) {
    const int bsel = t & 1;
    const short* Kb = (const short*)(smem_raw + bsel * 16384);
    const short* Vb = (const short*)(smem_raw + 32768 + bsel * 16384);
    if (t + 1 < ntiles) issue_loads(t + 1);

    // ---- kf cache: this wave's 32-kv half, reused for both subtiles ----
    bf16x8 kf[2][4];
#pragma unroll
    for (int cs = 0; cs < 2; ++cs)
#pragma unroll
      for (int db = 0; db < 4; ++db)
        kf[cs][db] = *(const bf16x8*)&Kb[kidx(kvh * 32 + cs * 16 + lo, db * 32 + hi * 8)];

    // ---- S^T = K Q^T : sacc[sub][cs][i] = S[q=lo][kv=cs*16+hi*4+i] ----
    f32x4 sacc[2][2];
#pragma unroll
    for (int s = 0; s < 2; ++s)
#pragma unroll
      for (int cs = 0; cs < 2; ++cs) sacc[s][cs] = (f32x4){0.f, 0.f, 0.f, 0.f};
#pragma unroll
    for (int cs = 0; cs < 2; ++cs)
#pragma unroll
      for (int db = 0; db < 4; ++db) {
#pragma unroll
        for (int sub = 0; sub < 2; ++sub)
          sacc[sub][cs] = __builtin_amdgcn_mfma_f32_16x16x32_bf16(
              kf[cs][db], qf[sub][db], sacc[sub][cs], 0, 0, 0);
      }

    // ---- in-register online softmax + pa pack, per subtile ----
    bf16x8 pa[2];
#pragma unroll
    for (int sub = 0; sub < 2; ++sub) {
      float mx;
      {
        float m0 = fmaxf(fmaxf(sacc[sub][0][0], sacc[sub][0][1]),
                         fmaxf(sacc[sub][0][2], sacc[sub][0][3]));
        float m1 = fmaxf(fmaxf(sacc[sub][1][0], sacc[sub][1][1]),
                         fmaxf(sacc[sub][1][2], sacc[sub][1][3]));
        mx = fmaxf(m0, m1);
        mx = fmaxf(mx, __shfl_xor(mx, 16));
        mx = fmaxf(mx, __shfl_xor(mx, 32));
      }
      const bool keep = __all(mx - mrow[sub] <= 8.0f);   // defer-max
      const float mnew = keep ? mrow[sub] : fmaxf(mrow[sub], mx);
      float rs = 0.f;
#pragma unroll
      for (int cs = 0; cs < 2; ++cs)
#pragma unroll
        for (int i = 0; i < 4; ++i) {
          const float p = __expf(sacc[sub][cs][i] - mnew);
          sacc[sub][cs][i] = p;
          rs += p;
        }
      rs += __shfl_xor(rs, 16);
      rs += __shfl_xor(rs, 32);
      if (keep) {
        lrow[sub] += rs;
      } else {
        const float sc = __expf(mrow[sub] - mnew);
        lrow[sub] = lrow[sub] * sc + rs;
        mrow[sub] = mnew;
#pragma unroll
        for (int dt = 0; dt < 8; ++dt) oacc[sub][dt] *= sc;
      }
      bf8u p;
      p.u[0] = cvt_pk2(sacc[sub][0][0], sacc[sub][0][1]);
      p.u[1] = cvt_pk2(sacc[sub][0][2], sacc[sub][0][3]);
      p.u[2] = cvt_pk2(sacc[sub][1][0], sacc[sub][1][1]);
      p.u[3] = cvt_pk2(sacc[sub][1][2], sacc[sub][1][3]);
      pa[sub] = p.v;
    }

    // ---- O^T += V^T P^T : vf read once, used for both subtiles ----
#pragma unroll
    for (int dt = 0; dt < 8; ++dt) {
      bf16x8 vf = *(const bf16x8*)&Vb[vidx(dt * 16 + lo, kvh * 32 + hi * 8)];
#pragma unroll
      for (int sub = 0; sub < 2; ++sub)
        oacc[sub][dt] = __builtin_amdgcn_mfma_f32_16x16x32_bf16(
            vf, pa[sub], oacc[sub][dt], 0, 0, 0);
    }

    if (t + 1 < ntiles) write_lds(bsel ^ 1);
    __syncthreads();
  }

  // ---- merge kv-halves: odd waves publish, even waves combine + store ----
  if (kvh == 1) {
#pragma unroll
    for (int sub = 0; sub < 2; ++sub) {
      const int g2 = qg2 * 2 + sub;
#pragma unroll
      for (int dt = 0; dt < 8; ++dt)
        *(f32x4*)&Os[(size_t)(g2 * 16 + lo) * 128 + dt * 16 + hi * 4] = oacc[sub][dt];
      if (hi == 0) { ms[g2][lo] = mrow[sub]; ls[g2][lo] = lrow[sub]; }
    }
  }
  __syncthreads();
  if (kvh == 0) {
#pragma unroll
    for (int sub = 0; sub < 2; ++sub) {
      const int g2 = qg2 * 2 + sub;
      const float m1 = ms[g2][lo], l1 = ls[g2][lo];
      const float mstar = fmaxf(mrow[sub], m1);
      const float a0 = __expf(mrow[sub] - mstar);
      const float a1 = __expf(m1 - mstar);
      const float linv = 1.f / (lrow[sub] * a0 + l1 * a1);
      float* orow = out + ((size_t)(b * LQ_ + qrow0 + sub * 16 + lo) * HQ_ + hq) * D_;
#pragma unroll
      for (int dt = 0; dt < 8; ++dt) {
        f32x4 o1 = *(const f32x4*)&Os[(size_t)(g2 * 16 + lo) * 128 + dt * 16 + hi * 4];
        f32x4 o = (oacc[sub][dt] * a0 + o1 * a1) * linv;
        *(f32x4*)(orow + dt * 16 + hi * 4) = o;
      }
    }
  }
}

extern "C" void kernel_launch(void* const* d_in, const int* in_sizes, int n_in,
                              void* d_out, int out_size, void* d_ws, size_t ws_size,
                              hipStream_t stream) {
  (void)in_sizes; (void)n_in; (void)out_size; (void)d_ws; (void)ws_size;
  const float* q      = (const float*)d_in[0];
  const float* k      = (const float*)d_in[1];
  const float* v      = (const float*)d_in[2];
  const float* kcache = (const float*)d_in[3];
  const float* vcache = (const float*)d_in[4];
  const int*   btab   = (const int*)d_in[5];
  float* out = (float*)d_out;

  block_attn_kernel<<<dim3(B_ * HKV_ * (LQ_ / 64)), dim3(512), 0, stream>>>(
      q, k, v, kcache, vcache, btab, out);
}